// Round 11
// baseline (31.562 us; speedup 1.0000x reference)
//
#include <hip/hip_runtime.h>
#include <hip/hip_fp16.h>

#define NPART 500000
#define MPART 450000
#define NBXC 1024
#define NBYC 1024
#define NPARTIAL 512            // field blocks
#define NBLK2 3907              // ceil(2*500000/256)

// Tiled field layout: 2x8-cell tiles (2 x-rows x 8 y-cells x 4B = 64B = one
// L2 sector). tile (tx,ty), tx=x>>1, ty=y>>3, tx-major.
// cell index = ((tx*128 + ty)*16) + (x&1)*8 + (y&7)
__device__ __forceinline__ int tidx(int x, int y) {
    return ((((x >> 1) * 128 + (y >> 3)) << 4) + ((x & 1) << 3) + (y & 7));
}

// ---------------------------------------------------------------------------
// Kernel A: velocity field. One thread = one tile-row (row x, cells
// j0..j0+7) -> 32B contiguous store. 512 blocks -> partials[512].
// ---------------------------------------------------------------------------
__global__ __launch_bounds__(256) void field_kernel(const float* __restrict__ pot,
                                                    const float* __restrict__ rho,
                                                    __half2* __restrict__ v,
                                                    float* __restrict__ partials) {
    const int idx = blockIdx.x * 256 + threadIdx.x;      // 0 .. 131071
    const int x  = idx >> 7;                             // row 0..1023
    const int ty = idx & 127;                            // y-tile 0..127
    const int j0 = ty << 3;                              // col 0,8,..,1016

    const int ip = min(x + 1, NBXC - 1);
    const int im = max(x - 1, 0);
    const float sx = (ip - im == 2) ? 0.5f : 1.0f;

    const float4* pc = reinterpret_cast<const float4*>(pot + x  * NBYC + j0);
    const float4* pu = reinterpret_cast<const float4*>(pot + ip * NBYC + j0);
    const float4* pd = reinterpret_cast<const float4*>(pot + im * NBYC + j0);
    const float4* pr = reinterpret_cast<const float4*>(rho + x  * NBYC + j0);
    float c[8], u[8], d[8], r[8];
    *reinterpret_cast<float4*>(c)     = pc[0]; *reinterpret_cast<float4*>(c + 4) = pc[1];
    *reinterpret_cast<float4*>(u)     = pu[0]; *reinterpret_cast<float4*>(u + 4) = pu[1];
    *reinterpret_cast<float4*>(d)     = pd[0]; *reinterpret_cast<float4*>(d + 4) = pd[1];
    *reinterpret_cast<float4*>(r)     = pr[0]; *reinterpret_cast<float4*>(r + 4) = pr[1];
    const float cl = pot[x * NBYC + max(j0 - 1, 0)];
    const float cr = pot[x * NBYC + min(j0 + 8, NBYC - 1)];

    float vx[8], vy[8];
    #pragma unroll
    for (int k = 0; k < 8; ++k) vx[k] = -(u[k] - d[k]) * sx;
    vy[0] = (j0 == 0) ? -(c[1] - c[0]) : -(c[1] - cl) * 0.5f;
    #pragma unroll
    for (int k = 1; k < 7; ++k) vy[k] = -(c[k + 1] - c[k - 1]) * 0.5f;
    vy[7] = (j0 + 7 == NBYC - 1) ? -(c[7] - c[6]) : -(cr - c[6]) * 0.5f;

    float st[8];
    #pragma unroll
    for (int k = 0; k < 8; ++k)
        st[k] = __builtin_bit_cast(float, __floats2half2_rn(vx[k], vy[k]));
    float4* vp = reinterpret_cast<float4*>(v + ((((x >> 1) * 128 + ty) << 4) + ((x & 1) << 3)));
    vp[0] = *reinterpret_cast<float4*>(st);
    vp[1] = *reinterpret_cast<float4*>(st + 4);

    float e = 0.0f;
    #pragma unroll
    for (int k = 0; k < 8; ++k) e += r[k] * (vx[k] * vx[k] + vy[k] * vy[k]);
    #pragma unroll
    for (int off = 32; off > 0; off >>= 1) e += __shfl_down(e, off, 64);
    __shared__ float smem[4];
    const int lane = threadIdx.x & 63;
    const int wid  = threadIdx.x >> 6;
    if (lane == 0) smem[wid] = e;
    __syncthreads();
    if (threadIdx.x == 0) partials[blockIdx.x] = (smem[0] + smem[1]) + (smem[2] + smem[3]);
}

// ---------------------------------------------------------------------------
// Kernel C: 2 threads per particle (lanes 2k,2k+1 -> particle k). Each half
// handles tile-pairs {half, half+2}; one shfl_xor combines. Halves the
// per-thread dependent load-cluster chain and doubles wave-level parallelism
// at unchanged total gather traffic. Block NBLK2 does the energy reduction.
// ---------------------------------------------------------------------------
__global__ __launch_bounds__(256) void particle_kernel(const float* __restrict__ pos,
                                                       const float* __restrict__ nsx,
                                                       const float* __restrict__ nsy,
                                                       const __half2* __restrict__ v,
                                                       const float* __restrict__ partials,
                                                       float* __restrict__ out) {
    __shared__ float smem[4];

    if (blockIdx.x == NBLK2) {          // ---- energy reduction block ----
        const int t = threadIdx.x;
        float e = partials[t] + partials[t + 256];
        #pragma unroll
        for (int off = 32; off > 0; off >>= 1) e += __shfl_down(e, off, 64);
        const int lane = t & 63;
        const int wid  = t >> 6;
        if (lane == 0) smem[wid] = e;
        __syncthreads();
        if (t == 0) out[0] = 0.5f * ((smem[0] + smem[1]) + (smem[2] + smem[3]));
        return;
    }

    const int t    = blockIdx.x * 256 + threadIdx.x;
    const int i    = t >> 1;
    const int half = t & 1;
    if (i >= NPART) return;
    if (i >= MPART) {                   // zero pad regions [M:N), [N+M:2N)
        if (half == 0) {
            out[1 + i]         = 0.0f;
            out[1 + NPART + i] = 0.0f;
        }
        return;
    }

    const float px = pos[i];
    const float py = pos[NPART + i];
    const float w  = nsx[i];
    const float h  = nsy[i];

    float afx = 0.0f, afy = 0.0f;
    const bool large = (w >= 1.0f) || (h >= 1.0f);
    if (!large) {
        if (half == 0) {                // 4 taps on even lane only; odd adds 0
            int ix = min(max((int)floorf(px), 0), NBXC - 1);
            int iy = min(max((int)floorf(py), 0), NBYC - 1);
            const float wx = fminf(fmaxf(px - (float)ix, 0.0f), 1.0f);
            const float wy = fminf(fmaxf(py - (float)iy, 0.0f), 1.0f);
            const int ix1 = min(ix + 1, NBXC - 1);
            const int iy1 = min(iy + 1, NBYC - 1);
            const float2 f00 = __half22float2(v[tidx(ix,  iy )]);
            const float2 f10 = __half22float2(v[tidx(ix1, iy )]);
            const float2 f01 = __half22float2(v[tidx(ix,  iy1)]);
            const float2 f11 = __half22float2(v[tidx(ix1, iy1)]);
            const float w00 = (1.0f - wx) * (1.0f - wy);
            const float w10 = wx * (1.0f - wy);
            const float w01 = (1.0f - wx) * wy;
            const float w11 = wx * wy;
            afx = w00 * f00.x + w10 * f10.x + w01 * f01.x + w11 * f11.x;
            afy = w00 * f00.y + w10 * f10.y + w01 * f01.y + w11 * f11.y;
        }
    } else {
        const float lx = px - 0.5f * w, rx = px + 0.5f * w;
        const float ly = py - 0.5f * h, ry = py + 0.5f * h;
        const int bminx = min(max((int)floorf(lx), 0), NBXC - 1);
        const int bmaxx = min(max((int)floorf(rx), 0), NBXC - 1);
        const int bminy = min(max((int)floorf(ly), 0), NBYC - 1);
        const int bmaxy = min(max((int)floorf(ry), 0), NBYC - 1);
        const int by0 = min(bminy & ~7, NBYC - 16);   // <=2 y-tiles always
        const int ty0 = by0 >> 3;
        const int bx0 = bminx & ~1;
        const bool y2 = (bmaxy - by0) >= 8;

        float oy[16];
        #pragma unroll
        for (int k = 0; k < 16; ++k) {
            const int b = by0 + k;
            const float bl = (float)b;
            float ov = fminf(ry, bl + 1.0f) - fmaxf(ly, bl);
            oy[k] = (b <= bmaxy && ov > 0.0f) ? ov : 0.0f;
        }

        const float4 z = make_float4(0.0f, 0.0f, 0.0f, 0.0f);
        #pragma unroll
        for (int pp = 0; pp < 2; ++pp) {
            const int p = half + 2 * pp;            // this half's tile-pairs
            float ov0, ov1;
            {
                const int b0c = bx0 + 2 * p, b1c = bx0 + 2 * p + 1;
                float o0 = fminf(rx, (float)b0c + 1.0f) - fmaxf(lx, (float)b0c);
                float o1 = fminf(rx, (float)b1c + 1.0f) - fmaxf(lx, (float)b1c);
                ov0 = (b0c <= bmaxx && o0 > 0.0f) ? o0 : 0.0f;
                ov1 = (b1c <= bmaxx && o1 > 0.0f) ? o1 : 0.0f;
            }
            if (ov0 > 0.0f || ov1 > 0.0f) {         // exec-masked tile-pair
                const float4* tp = reinterpret_cast<const float4*>(
                    v + (((((bx0 >> 1) + p) * 128 + ty0) << 4)));
                float4 A0 = tp[0], A1 = tp[1], B0 = tp[2], B1 = tp[3];
                float4 A2 = z, A3 = z, B2 = z, B3 = z;
                if (y2) { A2 = tp[4]; A3 = tp[5]; B2 = tp[6]; B3 = tp[7]; }
                float sxa = 0.0f, sya = 0.0f, sxb = 0.0f, syb = 0.0f;
                const float* a0 = &A0.x; const float* a1 = &A1.x;
                const float* a2 = &A2.x; const float* a3 = &A3.x;
                const float* b0 = &B0.x; const float* b1 = &B1.x;
                const float* b2 = &B2.x; const float* b3 = &B3.x;
                #pragma unroll
                for (int e = 0; e < 4; ++e) {
                    float2 f;
                    f = __half22float2(__builtin_bit_cast(__half2, a0[e]));
                    sxa += f.x * oy[e];      sya += f.y * oy[e];
                    f = __half22float2(__builtin_bit_cast(__half2, a1[e]));
                    sxa += f.x * oy[4 + e];  sya += f.y * oy[4 + e];
                    f = __half22float2(__builtin_bit_cast(__half2, a2[e]));
                    sxa += f.x * oy[8 + e];  sya += f.y * oy[8 + e];
                    f = __half22float2(__builtin_bit_cast(__half2, a3[e]));
                    sxa += f.x * oy[12 + e]; sya += f.y * oy[12 + e];
                    f = __half22float2(__builtin_bit_cast(__half2, b0[e]));
                    sxb += f.x * oy[e];      syb += f.y * oy[e];
                    f = __half22float2(__builtin_bit_cast(__half2, b1[e]));
                    sxb += f.x * oy[4 + e];  syb += f.y * oy[4 + e];
                    f = __half22float2(__builtin_bit_cast(__half2, b2[e]));
                    sxb += f.x * oy[8 + e];  syb += f.y * oy[8 + e];
                    f = __half22float2(__builtin_bit_cast(__half2, b3[e]));
                    sxb += f.x * oy[12 + e]; syb += f.y * oy[12 + e];
                }
                afx += sxa * ov0 + sxb * ov1;
                afy += sya * ov0 + syb * ov1;
            }
        }
    }

    // combine the two halves (lanes 2k <-> 2k+1)
    afx += __shfl_xor(afx, 1, 64);
    afy += __shfl_xor(afy, 1, 64);
    if (half == 0) {
        const float inv = 1.0f / fmaxf(w * h, 1e-30f);
        out[1 + i]         = large ? afx * inv : afx;
        out[1 + NPART + i] = large ? afy * inv : afy;
    }
}

extern "C" void kernel_launch(void* const* d_in, const int* in_sizes, int n_in,
                              void* d_out, int out_size, void* d_ws, size_t ws_size,
                              hipStream_t stream) {
    const float* pos = (const float*)d_in[0];
    const float* pot = (const float*)d_in[1];
    const float* rho = (const float*)d_in[2];
    const float* nsx = (const float*)d_in[3];
    const float* nsy = (const float*)d_in[4];
    float* out = (float*)d_out;

    __half2* v      = (__half2*)d_ws;                                     // 4 MB (2x8 tiled)
    float* partials = (float*)((char*)d_ws + (size_t)NBXC * NBYC * sizeof(__half2));

    field_kernel<<<NPARTIAL, 256, 0, stream>>>(pot, rho, v, partials);
    particle_kernel<<<NBLK2 + 1, 256, 0, stream>>>(pos, nsx, nsy, v, partials, out);
}